// Round 11
// baseline (219.025 us; speedup 1.0000x reference)
//
#include <hip/hip_runtime.h>

// GeoCyclicPadding: x (B=2, C=192, H=360, W=720) f32, p=3 -> out (B,C,366,726)
//
// R9 + 2 CONSECUTIVE float4 groups per bulk thread (32B/thread):
//  - preserves the device-wide linear sweep (R10 proved row-strided quads
//    break DRAM stream locality and regress),
//  - halves wave count, amortizes index math, 2 loads in flight.
//  BULK (48,600 blocks): thread copies x[bc,r,8k2..8k2+8) to
//    out[bc,r+3, 3+8k2..) -- loads 16B-aligned, stores misaligned by 4/12B
//    (harmless: out rows are contiguous, L2 merges; R7 proved fixing it
//    costs more than it saves).
//  EDGE (6,507 blocks, unchanged from R9): per plane EPP=4338 jobs:
//    q<2160: middle-row edge cols (scalar); else halo-row float2 groups.
//  Bresenham-interleaved so edge latency hides under the bulk BW stream.

typedef float f4a __attribute__((ext_vector_type(4), aligned(16)));
typedef float f4u __attribute__((ext_vector_type(4), aligned(4)));
typedef float f2u __attribute__((ext_vector_type(2), aligned(4)));

__global__ __launch_bounds__(256) void geo_pad_kernel(const float* __restrict__ x,
                                                      float* __restrict__ out) {
    constexpr int W = 720, H = 360, p = 3, Wp = 726, Hp = 366;
    constexpr unsigned EPP  = 2160u + 6u * 363u;        // 4338 edge jobs/plane
    constexpr unsigned EBLK = 384u * EPP / 256u;        // 6,507 edge blocks
    constexpr unsigned BBLK = 384u * 360u * 90u / 256u; // 48,600 bulk blocks
    constexpr unsigned TBLK = BBLK + EBLK;              // 55,107

    const unsigned i = blockIdx.x;
    const unsigned long long iE = (unsigned long long)i * EBLK;
    const unsigned e_before = (unsigned)(iE / TBLK);
    const unsigned e_after  = (unsigned)((iE + EBLK) / TBLK);

    if (e_after == e_before) {
        // ---- bulk: 2 consecutive aligned float4 copies per thread ----
        const unsigned t = (i - e_before) * 256u + threadIdx.x;
        const unsigned k2 = t % 90u;           // pair index: groups 2k2, 2k2+1
        const unsigned rr = t / 90u;
        const unsigned r  = rr % 360u;
        const unsigned bc = rr / 360u;

        const float* __restrict__ s0 =
            x + (size_t)(bc * 360u + r) * W + 8u * k2;
        float* __restrict__ d0 =
            out + ((size_t)bc * Hp + (r + 3)) * Wp + 3 + 8u * k2;

        f4a v0 = __builtin_nontemporal_load(reinterpret_cast<const f4a*>(s0));
        f4a v1 = __builtin_nontemporal_load(reinterpret_cast<const f4a*>(s0 + 4));

        f4u a0; a0.x = v0.x; a0.y = v0.y; a0.z = v0.z; a0.w = v0.w;
        f4u a1; a1.x = v1.x; a1.y = v1.y; a1.z = v1.z; a1.w = v1.w;
        __builtin_nontemporal_store(a0, reinterpret_cast<f4u*>(d0));
        __builtin_nontemporal_store(a1, reinterpret_cast<f4u*>(d0 + 4));
    } else {
        // ---- edges (identical to R9) ----
        const unsigned e = e_before * 256u + threadIdx.x;
        const unsigned bc = e / EPP;
        const unsigned q  = e % EPP;

        if (q < 2160u) {                       // middle-row edge columns
            const int r  = (int)(q / 6u);
            const int c6 = (int)(q % 6u);
            const int ho  = r + p;
            const int h   = r;
            const int col = (c6 < 3) ? c6 : (720 + c6);
            const int w   = (c6 < 3) ? (717 + c6) : (c6 - 3);
            out[((size_t)bc * Hp + ho) * Wp + col] =
                x[((size_t)bc * H + h) * W + w];
        } else {                               // halo rows, float2 groups
            const unsigned q2 = q - 2160u;     // [0, 2178)
            const unsigned g  = q2 % 363u;
            const int hr = (int)(q2 / 363u);   // 0..5
            const int ho = (hr < p) ? hr : (H + hr);
            const int h  = (hr < p) ? (p - 1 - hr) : (362 - hr);

            const float* __restrict__ srow = x + ((size_t)bc * H + h) * W;
            float* __restrict__ orow = out + ((size_t)bc * Hp + ho) * Wp;

            const int c0 = 2 * (int)g;
            int wr0 = c0 + 360; if (wr0 >= Wp) wr0 -= Wp;
            int wr1 = c0 + 361; if (wr1 >= Wp) wr1 -= Wp;
            int w0 = wr0 - p; if (w0 < 0) w0 += W; else if (w0 >= W) w0 -= W;
            int w1 = wr1 - p; if (w1 < 0) w1 += W; else if (w1 >= W) w1 -= W;

            f2u sv;
            if (w1 == w0 + 1) {
                sv = *reinterpret_cast<const f2u*>(srow + w0);
            } else {
                sv.x = srow[w0]; sv.y = srow[w1];
            }
            __builtin_nontemporal_store(sv, reinterpret_cast<f2u*>(orow + c0));
        }
    }
}

extern "C" void kernel_launch(void* const* d_in, const int* in_sizes, int n_in,
                              void* d_out, int out_size, void* d_ws, size_t ws_size,
                              hipStream_t stream) {
    const float* x = (const float*)d_in[0];
    float* out = (float*)d_out;

    // 48,600 bulk (2 consecutive float4/thread) + 6,507 edge = 55,107 blocks.
    geo_pad_kernel<<<55107u, 256, 0, stream>>>(x, out);
}

// Round 12
// 142.279 us; speedup vs baseline: 1.5394x; 1.5394x over previous
//
#include <hip/hip_runtime.h>

// GeoCyclicPadding: x (B=2, C=192, H=360, W=720) f32, p=3 -> out (B,C,366,726)
//
// FINAL (= R9, best known: 142.6 us, ~90% of the 6.29 TB/s copy ceiling).
//  BULK (97,200 blocks): out[bc, 3+r, 3+w] = x[bc, r, w] -- thread k copies
//    16B-ALIGNED src group x[bc,r,4k..4k+4) to out[bc,3+r,3+4k..) (store
//    misaligned by 4/12B; R7 proved fixing this costs more than it saves;
//    R10/R11 proved any deviation from lane-unit-stride block-linear
//    mapping breaks coalescing or DRAM sweep locality and regresses).
//  EDGE (6,507 blocks), per plane EPP = 4338 jobs:
//    q in [0,2160): middle-row edge cols, 1 scalar elem per job
//    q in [2160,4338): halo-row float2 groups (wrap fallback)
//  Blocks Bresenham-interleaved (edge block every ~16th) so edge work
//  overlaps the bulk BW stream instead of forming a low-BW tail phase.

typedef float f4a __attribute__((ext_vector_type(4), aligned(16)));
typedef float f4u __attribute__((ext_vector_type(4), aligned(4)));
typedef float f2u __attribute__((ext_vector_type(2), aligned(4)));

__global__ __launch_bounds__(256) void geo_pad_kernel(const float* __restrict__ x,
                                                      float* __restrict__ out) {
    constexpr int W = 720, H = 360, p = 3, Wp = 726, Hp = 366;
    constexpr unsigned EPP  = 2160u + 6u * 363u;   // 4338 edge jobs / plane
    constexpr unsigned EBLK = 384u * EPP / 256u;   // 6,507 edge blocks (exact)
    constexpr unsigned TBLK = 97200u + EBLK;       // 103,707 total blocks

    const unsigned i = blockIdx.x;
    const unsigned long long iE = (unsigned long long)i * EBLK;
    const unsigned e_before = (unsigned)(iE / TBLK);
    const unsigned e_after  = (unsigned)((iE + EBLK) / TBLK);

    if (e_after == e_before) {
        // ---- bulk: aligned-load strided copy ----
        const unsigned t = (i - e_before) * 256u + threadIdx.x;
        const unsigned k  = t % 180u;
        const unsigned rr = t / 180u;
        const unsigned r  = rr % 360u;
        const unsigned bc = rr / 360u;

        const f4a* src = reinterpret_cast<const f4a*>(
            x + (size_t)(bc * 360u + r) * W) + k;
        f4a v = __builtin_nontemporal_load(src);

        float* dst = out + ((size_t)bc * Hp + (r + 3)) * Wp + 3 + 4 * k;
        f4u sv; sv.x = v.x; sv.y = v.y; sv.z = v.z; sv.w = v.w;
        __builtin_nontemporal_store(sv, reinterpret_cast<f4u*>(dst));
    } else {
        // ---- edges ----
        const unsigned e = e_before * 256u + threadIdx.x;
        const unsigned bc = e / EPP;
        const unsigned q  = e % EPP;

        if (q < 2160u) {                       // middle-row edge columns
            const int r  = (int)(q / 6u);
            const int c6 = (int)(q % 6u);
            const int ho  = r + p;
            const int h   = r;
            const int col = (c6 < 3) ? c6 : (720 + c6);
            const int w   = (c6 < 3) ? (717 + c6) : (c6 - 3);
            out[((size_t)bc * Hp + ho) * Wp + col] =
                x[((size_t)bc * H + h) * W + w];
        } else {                               // halo rows, float2 groups
            const unsigned q2 = q - 2160u;     // [0, 2178)
            const unsigned g  = q2 % 363u;
            const int hr = (int)(q2 / 363u);   // 0..5
            const int ho = (hr < p) ? hr : (H + hr);
            const int h  = (hr < p) ? (p - 1 - hr) : (362 - hr);

            const float* __restrict__ srow = x + ((size_t)bc * H + h) * W;
            float* __restrict__ orow = out + ((size_t)bc * Hp + ho) * Wp;

            const int c0 = 2 * (int)g;
            int wr0 = c0 + 360; if (wr0 >= Wp) wr0 -= Wp;
            int wr1 = c0 + 361; if (wr1 >= Wp) wr1 -= Wp;
            int w0 = wr0 - p; if (w0 < 0) w0 += W; else if (w0 >= W) w0 -= W;
            int w1 = wr1 - p; if (w1 < 0) w1 += W; else if (w1 >= W) w1 -= W;

            f2u sv;
            if (w1 == w0 + 1) {
                sv = *reinterpret_cast<const f2u*>(srow + w0);
            } else {
                sv.x = srow[w0]; sv.y = srow[w1];
            }
            __builtin_nontemporal_store(sv, reinterpret_cast<f2u*>(orow + c0));
        }
    }
}

extern "C" void kernel_launch(void* const* d_in, const int* in_sizes, int n_in,
                              void* d_out, int out_size, void* d_ws, size_t ws_size,
                              hipStream_t stream) {
    const float* x = (const float*)d_in[0];
    float* out = (float*)d_out;

    // 97,200 bulk + 6,507 edge = 103,707 blocks, interleaved in-kernel.
    geo_pad_kernel<<<103707u, 256, 0, stream>>>(x, out);
}